// Round 4
// baseline (3964.220 us; speedup 1.0000x reference)
//
#include <hip/hip_runtime.h>
#include <hip/hip_bf16.h>

typedef unsigned short ushort_t;
typedef unsigned int uint_t;
typedef __attribute__((ext_vector_type(8))) short short8;
typedef __attribute__((ext_vector_type(4))) float f32x4;

#define DIMC 256
#define D_INNER 512
#define D_STATE 64
#define DT_RANK 16
#define LSEQ 4096
#define BS2 8            // 2*BS batches through mamba
#define MROWS (BS2*LSEQ) // 32768

__device__ __forceinline__ float b2f(ushort_t u) {
    union { uint_t i; float f; } v; v.i = ((uint_t)u) << 16; return v.f;
}
__device__ __forceinline__ ushort_t f2b(float f) {
    union { float f; uint_t i; } v; v.f = f;
    uint_t r = v.i + 0x7FFFu + ((v.i >> 16) & 1u);   // RNE
    return (ushort_t)(r >> 16);
}

// ---------------- fp32 -> bf16 weight conversion ----------------
__global__ void cvtw(const float* __restrict__ src, ushort_t* __restrict__ dst, int n) {
    int i = blockIdx.x * 256 + threadIdx.x;
    if (i < n) dst[i] = f2b(src[i]);
}

// ---------------- LN1 + build xm (both orders), fp32 in, bf16 out ----------------
__global__ void ln1_build_xm(const float* __restrict__ x,
                             const float* __restrict__ w,
                             const float* __restrict__ bb,
                             ushort_t* __restrict__ xm) {
    int row = blockIdx.x;            // b*4096 + l  (b in 0..3)
    int c = threadIdx.x;             // 0..255
    float v = x[(size_t)row * DIMC + c];
    float s1 = v, s2 = v * v;
    for (int off = 32; off; off >>= 1) {
        s1 += __shfl_xor(s1, off, 64);
        s2 += __shfl_xor(s2, off, 64);
    }
    __shared__ float sa[4], sb[4];
    int widx = c >> 6, lane = c & 63;
    if (lane == 0) { sa[widx] = s1; sb[widx] = s2; }
    __syncthreads();
    s1 = sa[0] + sa[1] + sa[2] + sa[3];
    s2 = sb[0] + sb[1] + sb[2] + sb[3];
    float mu = s1 * (1.0f / 256.0f);
    float var = s2 * (1.0f / 256.0f) - mu * mu;
    float xn = (v - mu) * rsqrtf(var + 1e-6f) * w[c] + bb[c];
    ushort_t o = f2b(xn);
    int b = row >> 12, l = row & 4095, i = l >> 6, j = l & 63;
    xm[((size_t)b * LSEQ + l) * DIMC + c] = o;
    xm[((size_t)(4 + b) * LSEQ + (j * 64 + i)) * DIMC + c] = o;
}

// ---------------- generic NT GEMM: C[M,N] = A[M,K] * W[N,K]^T (bf16 in/out) ----------------
// block = 256 (4 waves); wave computes 16 rows x 64 cols; grid (M/64, ceil(N/64))
__global__ void gemm_nt(const ushort_t* __restrict__ A,
                        const ushort_t* __restrict__ W,
                        ushort_t* __restrict__ C, int M, int N, int K) {
    int tid = threadIdx.x;
    int lane = tid & 63, widx = tid >> 6;
    int m0 = blockIdx.x * 64 + widx * 16;
    int n0 = blockIdx.y * 64;
    int l16 = lane & 15, quad = lane >> 4;
    f32x4 acc[4] = {f32x4{0,0,0,0}, f32x4{0,0,0,0}, f32x4{0,0,0,0}, f32x4{0,0,0,0}};
    const ushort_t* arow = A + (size_t)(m0 + l16) * K + quad * 8;
    bool nv[4];
    for (int j = 0; j < 4; ++j) nv[j] = (n0 + j * 16) < N;
    for (int k0 = 0; k0 < K; k0 += 32) {
        short8 af = *(const short8*)(arow + k0);
        #pragma unroll
        for (int j = 0; j < 4; ++j) {
            if (nv[j]) {
                const ushort_t* wrow = W + (size_t)(n0 + j * 16 + l16) * K + quad * 8 + k0;
                short8 bf = *(const short8*)wrow;
                acc[j] = __builtin_amdgcn_mfma_f32_16x16x32_bf16(af, bf, acc[j], 0, 0, 0);
            }
        }
    }
    #pragma unroll
    for (int j = 0; j < 4; ++j) {
        if (!nv[j]) continue;
        int col = n0 + j * 16 + l16;
        #pragma unroll
        for (int r = 0; r < 4; ++r) {
            int row = m0 + quad * 4 + r;
            C[(size_t)row * N + col] = f2b(acc[j][r]);
        }
    }
}

// ---------------- depthwise causal conv(4) + bias + SiLU ----------------
__global__ void conv_silu(const ushort_t* __restrict__ xh,
                          const float* __restrict__ cw,
                          const float* __restrict__ cb,
                          ushort_t* __restrict__ xc) {
    size_t gid = (size_t)blockIdx.x * 256 + threadIdx.x;  // over 8*4096*512
    int d = (int)(gid & 511);
    size_t bt = gid >> 9;       // b*4096 + t
    int t = (int)(bt & 4095);
    float acc = cb[d];
    #pragma unroll
    for (int k = 0; k < 4; ++k) {
        int tt = t - 3 + k;
        if (tt >= 0)
            acc += cw[d * 4 + k] * b2f(xh[(bt - 3 + k) * 512 + d]);
    }
    float s = acc / (1.0f + __expf(-acc));
    xc[gid] = f2b(s);
}

// ---------------- dt = softplus(dt_raw @ W_dt^T + b_dt) ----------------
__global__ void dt_softplus(const ushort_t* __restrict__ xdbl,
                            const float* __restrict__ wdt,
                            const float* __restrict__ bdt,
                            ushort_t* __restrict__ dt) {
    size_t gid = (size_t)blockIdx.x * 256 + threadIdx.x;
    int d = (int)(gid & 511);
    size_t bt = gid >> 9;
    const ushort_t* r = xdbl + bt * 144;
    float acc = bdt[d];
    #pragma unroll
    for (int k = 0; k < 16; ++k)
        acc += b2f(r[k]) * wdt[d * 16 + k];
    float sp = (acc > 20.0f) ? acc : log1pf(__expf(acc));
    dt[gid] = f2b(sp);
}

// ---------------- selective scan: wave per (b,d), lane = state s ----------------
// xc_ys: read u, write y IN PLACE
__global__ void scan_kernel(ushort_t* xc_ys,
                            const ushort_t* __restrict__ dt,
                            const ushort_t* __restrict__ xdbl,
                            const ushort_t* __restrict__ zb,
                            const float* __restrict__ Alog,
                            const float* __restrict__ Dp) {
    int wid = blockIdx.x * 4 + (threadIdx.x >> 6);  // 0..4095
    int lane = threadIdx.x & 63;
    int b = wid >> 9, d = wid & 511;
    float a = -__expf(Alog[d * 64 + lane]);
    float Dd = Dp[d];
    float h = 0.0f;
    size_t base = (size_t)b * LSEQ;
    for (int t = 0; t < LSEQ; ++t) {
        size_t bt = base + t;
        float dtv = b2f(dt[bt * 512 + d]);
        float uv  = b2f(xc_ys[bt * 512 + d]);
        float Bv  = b2f(xdbl[bt * 144 + 16 + lane]);
        float Cv  = b2f(xdbl[bt * 144 + 80 + lane]);
        float dA = __expf(dtv * a);
        h = dA * h + (dtv * uv) * Bv;
        float p = h * Cv;
        for (int off = 32; off; off >>= 1) p += __shfl_xor(p, off, 64);
        if (lane == 0) {
            float zv = b2f(zb[bt * 512 + d]);
            float y = p + uv * Dd;
            y *= zv / (1.0f + __expf(-zv));
            xc_ys[bt * 512 + d] = f2b(y);
        }
    }
}

// ---------------- final LN + transpose-combine + residual (fp32 out) ----------------
__global__ void final_ln_add(const ushort_t* __restrict__ outm,
                             const float* __restrict__ x,
                             const float* __restrict__ w,
                             const float* __restrict__ bb,
                             float* __restrict__ out) {
    int row = blockIdx.x;   // b*4096 + l, b in 0..3
    int c = threadIdx.x;
    int b = row >> 12, l = row & 4095, i = l >> 6, j = l & 63;
    size_t rA = ((size_t)b * LSEQ + l) * DIMC;
    size_t rB = ((size_t)(4 + b) * LSEQ + (j * 64 + i)) * DIMC;
    float va = b2f(outm[rA + c]);
    float vb = b2f(outm[rB + c]);
    float s1 = va, s2 = va * va, s3 = vb, s4 = vb * vb;
    for (int off = 32; off; off >>= 1) {
        s1 += __shfl_xor(s1, off, 64);
        s2 += __shfl_xor(s2, off, 64);
        s3 += __shfl_xor(s3, off, 64);
        s4 += __shfl_xor(s4, off, 64);
    }
    __shared__ float sm[4][4];
    int widx = c >> 6, lane = c & 63;
    if (lane == 0) { sm[widx][0] = s1; sm[widx][1] = s2; sm[widx][2] = s3; sm[widx][3] = s4; }
    __syncthreads();
    s1 = sm[0][0] + sm[1][0] + sm[2][0] + sm[3][0];
    s2 = sm[0][1] + sm[1][1] + sm[2][1] + sm[3][1];
    s3 = sm[0][2] + sm[1][2] + sm[2][2] + sm[3][2];
    s4 = sm[0][3] + sm[1][3] + sm[2][3] + sm[3][3];
    float muA = s1 * (1.0f / 256.0f), varA = s2 * (1.0f / 256.0f) - muA * muA;
    float muB = s3 * (1.0f / 256.0f), varB = s4 * (1.0f / 256.0f) - muB * muB;
    float lw = w[c], lb = bb[c];
    float ya = (va - muA) * rsqrtf(varA + 1e-6f) * lw + lb;
    float yb = (vb - muB) * rsqrtf(varB + 1e-6f) * lw + lb;
    float xo = x[(size_t)row * DIMC + c];
    out[(size_t)row * DIMC + c] = xo + ya + yb;
}

extern "C" void kernel_launch(void* const* d_in, const int* in_sizes, int n_in,
                              void* d_out, int out_size, void* d_ws, size_t ws_size,
                              hipStream_t stream) {
    const float* x      = (const float*)d_in[0];
    const float* ln1_w  = (const float*)d_in[1];
    const float* ln1_b  = (const float*)d_in[2];
    const float* ln2_w  = (const float*)d_in[3];
    const float* ln2_b  = (const float*)d_in[4];
    const float* W_in   = (const float*)d_in[5];
    const float* conv_w = (const float*)d_in[6];
    const float* conv_b = (const float*)d_in[7];
    const float* W_x    = (const float*)d_in[8];
    const float* W_dt   = (const float*)d_in[9];
    const float* b_dt   = (const float*)d_in[10];
    const float* A_log  = (const float*)d_in[11];
    const float* D_par  = (const float*)d_in[12];
    const float* W_out  = (const float*)d_in[13];
    float* out = (float*)d_out;

    // ---- workspace ----
    char* ws = (char*)d_ws;
    size_t off = 0;
    ushort_t* wb_in  = (ushort_t*)(ws + off); off += (size_t)1024 * 256 * 2;   // 512 KB
    ushort_t* wb_x   = (ushort_t*)(ws + off); off += (size_t)144 * 512 * 2;    // 144 KB
    ushort_t* wb_out = (ushort_t*)(ws + off); off += (size_t)256 * 512 * 2;    // 256 KB
    const size_t R0 = (size_t)MROWS * DIMC * 2;   // 16.78 MB
    const size_t R1 = (size_t)MROWS * 512 * 2;    // 33.55 MB
    ushort_t* r0 = (ushort_t*)(ws + off); off += R0;   // xm -> xdbl -> outm
    ushort_t* r1 = (ushort_t*)(ws + off); off += R1;   // xhalf -> dt
    ushort_t* r2 = (ushort_t*)(ws + off); off += R1;   // z
    ushort_t* r3 = (ushort_t*)(ws + off); off += R1;   // xc -> ys (in place)

    ushort_t* xm    = r0;
    ushort_t* xdbl  = r0;
    ushort_t* outm  = r0;
    ushort_t* xhalf = r1;
    ushort_t* dt    = r1;
    ushort_t* zb    = r2;
    ushort_t* xc    = r3;

    // 0. convert MFMA weights fp32 -> bf16
    hipLaunchKernelGGL(cvtw, dim3((1024 * 256 + 255) / 256), dim3(256), 0, stream,
                       W_in, wb_in, 1024 * 256);
    hipLaunchKernelGGL(cvtw, dim3((144 * 512 + 255) / 256), dim3(256), 0, stream,
                       W_x, wb_x, 144 * 512);
    hipLaunchKernelGGL(cvtw, dim3((256 * 512 + 255) / 256), dim3(256), 0, stream,
                       W_out, wb_out, 256 * 512);

    // A. LayerNorm + dual-order xm
    hipLaunchKernelGGL(ln1_build_xm, dim3(4 * LSEQ), dim3(256), 0, stream,
                       x, ln1_w, ln1_b, xm);
    // B. xhalf = xm @ W_in[0:512]^T ; z = xm @ W_in[512:1024]^T
    hipLaunchKernelGGL(gemm_nt, dim3(MROWS / 64, 8), dim3(256), 0, stream,
                       xm, wb_in, xhalf, MROWS, 512, 256);
    hipLaunchKernelGGL(gemm_nt, dim3(MROWS / 64, 8), dim3(256), 0, stream,
                       xm, wb_in + (size_t)512 * 256, zb, MROWS, 512, 256);
    // C. conv + SiLU  (xhalf -> xc)
    hipLaunchKernelGGL(conv_silu, dim3((size_t)MROWS * 512 / 256), dim3(256), 0, stream,
                       xhalf, conv_w, conv_b, xc);
    // D. x_dbl = xc @ W_x^T   (N=144, K=512) -> region0
    hipLaunchKernelGGL(gemm_nt, dim3(MROWS / 64, 3), dim3(256), 0, stream,
                       xc, wb_x, xdbl, MROWS, 144, 512);
    // E. dt = softplus(dt_raw @ W_dt^T + b_dt) -> region1
    hipLaunchKernelGGL(dt_softplus, dim3((size_t)MROWS * 512 / 256), dim3(256), 0, stream,
                       xdbl, W_dt, b_dt, dt);
    // F. selective scan (+ *silu(z) fused), ys written over xc
    hipLaunchKernelGGL(scan_kernel, dim3(BS2 * 512 / 4), dim3(256), 0, stream,
                       xc, dt, xdbl, zb, A_log, D_par);
    // G. outm = ys @ W_out^T   (N=256, K=512) -> region0
    hipLaunchKernelGGL(gemm_nt, dim3(MROWS / 64, 4), dim3(256), 0, stream,
                       xc, wb_out, outm, MROWS, 256, 512);
    // H. final LN + transpose combine + residual (fp32 out)
    hipLaunchKernelGGL(final_ln_add, dim3(4 * LSEQ), dim3(256), 0, stream,
                       outm, x, ln2_w, ln2_b, out);
}

// Round 5
// 2320.142 us; speedup vs baseline: 1.7086x; 1.7086x over previous
//
#include <hip/hip_runtime.h>
#include <hip/hip_bf16.h>

typedef unsigned short ushort_t;
typedef unsigned int uint_t;
typedef __attribute__((ext_vector_type(8))) short short8;
typedef __attribute__((ext_vector_type(4))) float f32x4;

#define DIMC 256
#define D_INNER 512
#define D_STATE 64
#define DT_RANK 16
#define LSEQ 4096
#define BS2 8            // 2*BS batches through mamba
#define MROWS (BS2*LSEQ) // 32768

__device__ __forceinline__ float b2f(ushort_t u) {
    union { uint_t i; float f; } v; v.i = ((uint_t)u) << 16; return v.f;
}
__device__ __forceinline__ ushort_t f2b(float f) {
    union { float f; uint_t i; } v; v.f = f;
    uint_t r = v.i + 0x7FFFu + ((v.i >> 16) & 1u);   // RNE
    return (ushort_t)(r >> 16);
}
__device__ __forceinline__ float rdlane(float v, int l) {
    return __int_as_float(__builtin_amdgcn_readlane(__float_as_int(v), l));
}

// ---------------- fp32 -> bf16 weight conversion ----------------
__global__ void cvtw(const float* __restrict__ src, ushort_t* __restrict__ dst, int n) {
    int i = blockIdx.x * 256 + threadIdx.x;
    if (i < n) dst[i] = f2b(src[i]);
}

// ---------------- LN1 + build xm (both orders), fp32 in, bf16 out ----------------
__global__ void ln1_build_xm(const float* __restrict__ x,
                             const float* __restrict__ w,
                             const float* __restrict__ bb,
                             ushort_t* __restrict__ xm) {
    int row = blockIdx.x;            // b*4096 + l  (b in 0..3)
    int c = threadIdx.x;             // 0..255
    float v = x[(size_t)row * DIMC + c];
    float s1 = v, s2 = v * v;
    for (int off = 32; off; off >>= 1) {
        s1 += __shfl_xor(s1, off, 64);
        s2 += __shfl_xor(s2, off, 64);
    }
    __shared__ float sa[4], sb[4];
    int widx = c >> 6, lane = c & 63;
    if (lane == 0) { sa[widx] = s1; sb[widx] = s2; }
    __syncthreads();
    s1 = sa[0] + sa[1] + sa[2] + sa[3];
    s2 = sb[0] + sb[1] + sb[2] + sb[3];
    float mu = s1 * (1.0f / 256.0f);
    float var = s2 * (1.0f / 256.0f) - mu * mu;
    float xn = (v - mu) * rsqrtf(var + 1e-6f) * w[c] + bb[c];
    ushort_t o = f2b(xn);
    int b = row >> 12, l = row & 4095, i = l >> 6, j = l & 63;
    xm[((size_t)b * LSEQ + l) * DIMC + c] = o;
    xm[((size_t)(4 + b) * LSEQ + (j * 64 + i)) * DIMC + c] = o;
}

// ---------------- generic NT GEMM: C[M,N] = A[M,K] * W[N,K]^T (bf16 in/out) ----------------
__global__ void gemm_nt(const ushort_t* __restrict__ A,
                        const ushort_t* __restrict__ W,
                        ushort_t* __restrict__ C, int M, int N, int K) {
    int tid = threadIdx.x;
    int lane = tid & 63, widx = tid >> 6;
    int m0 = blockIdx.x * 64 + widx * 16;
    int n0 = blockIdx.y * 64;
    int l16 = lane & 15, quad = lane >> 4;
    f32x4 acc[4] = {f32x4{0,0,0,0}, f32x4{0,0,0,0}, f32x4{0,0,0,0}, f32x4{0,0,0,0}};
    const ushort_t* arow = A + (size_t)(m0 + l16) * K + quad * 8;
    bool nv[4];
    for (int j = 0; j < 4; ++j) nv[j] = (n0 + j * 16) < N;
    for (int k0 = 0; k0 < K; k0 += 32) {
        short8 af = *(const short8*)(arow + k0);
        #pragma unroll
        for (int j = 0; j < 4; ++j) {
            if (nv[j]) {
                const ushort_t* wrow = W + (size_t)(n0 + j * 16 + l16) * K + quad * 8 + k0;
                short8 bf = *(const short8*)wrow;
                acc[j] = __builtin_amdgcn_mfma_f32_16x16x32_bf16(af, bf, acc[j], 0, 0, 0);
            }
        }
    }
    #pragma unroll
    for (int j = 0; j < 4; ++j) {
        if (!nv[j]) continue;
        int col = n0 + j * 16 + l16;
        #pragma unroll
        for (int r = 0; r < 4; ++r) {
            int row = m0 + quad * 4 + r;
            C[(size_t)row * N + col] = f2b(acc[j][r]);
        }
    }
}

// ---------------- depthwise causal conv(4) + bias + SiLU ----------------
// writes xc [bt,d] (for GEMM D) AND u_T [b,d,t] (for scan)
__global__ void conv_silu(const ushort_t* __restrict__ xh,
                          const float* __restrict__ cw,
                          const float* __restrict__ cb,
                          ushort_t* __restrict__ xc,
                          ushort_t* __restrict__ u_T) {
    size_t gid = (size_t)blockIdx.x * 256 + threadIdx.x;  // over 8*4096*512
    int d = (int)(gid & 511);
    size_t bt = gid >> 9;       // b*4096 + t
    int t = (int)(bt & 4095);
    int b = (int)(bt >> 12);
    float acc = cb[d];
    #pragma unroll
    for (int k = 0; k < 4; ++k) {
        int tt = t - 3 + k;
        if (tt >= 0)
            acc += cw[d * 4 + k] * b2f(xh[(bt - 3 + k) * 512 + d]);
    }
    float s = acc / (1.0f + __expf(-acc));
    ushort_t o = f2b(s);
    xc[gid] = o;
    u_T[((size_t)b * 512 + d) * 4096 + t] = o;
}

// ---------------- dt = softplus(dt_raw @ W_dt^T + b_dt), transposed output ----------------
__global__ void dt_softplus(const ushort_t* __restrict__ xdbl,
                            const float* __restrict__ wdt,
                            const float* __restrict__ bdt,
                            ushort_t* __restrict__ dt_T) {
    size_t gid = (size_t)blockIdx.x * 256 + threadIdx.x;
    int d = (int)(gid & 511);
    size_t bt = gid >> 9;
    int t = (int)(bt & 4095);
    int b = (int)(bt >> 12);
    const ushort_t* r = xdbl + bt * 144;
    float acc = bdt[d];
    #pragma unroll
    for (int k = 0; k < 16; ++k)
        acc += b2f(r[k]) * wdt[d * 16 + k];
    float sp = (acc > 20.0f) ? acc : log1pf(__expf(acc));
    dt_T[((size_t)b * 512 + d) * 4096 + t] = f2b(sp);
}

// ---------------- selective scan v2: wave per (b,d), 64-t chunks ----------------
// per chunk: coalesced dt/u preload (lane=t), serial h-loop with readlane
// broadcasts, then 6-stage butterfly transpose-reduce -> lane holds y[t0+lane]
__global__ void scan2(const ushort_t* __restrict__ dt_T,
                      const ushort_t* __restrict__ u_T,
                      const ushort_t* __restrict__ xdbl,
                      const ushort_t* __restrict__ zb,
                      const float* __restrict__ Alog,
                      const float* __restrict__ Dp,
                      ushort_t* __restrict__ ys) {
    int wid = blockIdx.x * 4 + (threadIdx.x >> 6);  // 0..4095
    int lane = threadIdx.x & 63;
    int b = wid >> 9, d = wid & 511;
    float a = -__expf(Alog[d * 64 + lane]);
    float Dd = Dp[d];
    float h = 0.0f;
    size_t rowT = ((size_t)b * 512 + d) * 4096;
    size_t base = (size_t)b * LSEQ;
    for (int t0 = 0; t0 < LSEQ; t0 += 64) {
        // coalesced preloads: lane = local t
        float dtv = b2f(dt_T[rowT + t0 + lane]);
        float uv  = b2f(u_T [rowT + t0 + lane]);
        float zv  = b2f(zb[(base + t0 + lane) * 512 + d]);   // gather (used in epilogue)
        float wv  = dtv * uv;
        float p[64];
        #pragma unroll
        for (int j = 0; j < 64; ++j) {
            size_t r = (base + t0 + j) * 144;
            float Bv = b2f(xdbl[r + 16 + lane]);
            float Cv = b2f(xdbl[r + 80 + lane]);
            float dtb = rdlane(dtv, j);
            float wtb = rdlane(wv, j);
            float dA = __expf(dtb * a);
            h = dA * h + wtb * Bv;
            p[j] = h * Cv;
        }
        // butterfly transpose-reduce over s; result for t0+lane lands on lane
        #pragma unroll
        for (int mask = 32; mask >= 1; mask >>= 1) {
            bool up = (lane & mask) != 0;
            #pragma unroll
            for (int j2 = 0; j2 < mask; ++j2) {
                float send = up ? p[j2] : p[j2 + mask];
                float recv = __shfl_xor(send, mask, 64);
                float keep = up ? p[j2 + mask] : p[j2];
                p[j2] = keep + recv;
            }
        }
        float y = p[0] + uv * Dd;
        y *= zv / (1.0f + __expf(-zv));
        ys[(base + t0 + lane) * 512 + d] = f2b(y);   // scatter store
    }
}

// ---------------- final LN + transpose-combine + residual (fp32 out) ----------------
__global__ void final_ln_add(const ushort_t* __restrict__ outm,
                             const float* __restrict__ x,
                             const float* __restrict__ w,
                             const float* __restrict__ bb,
                             float* __restrict__ out) {
    int row = blockIdx.x;   // b*4096 + l, b in 0..3
    int c = threadIdx.x;
    int b = row >> 12, l = row & 4095, i = l >> 6, j = l & 63;
    size_t rA = ((size_t)b * LSEQ + l) * DIMC;
    size_t rB = ((size_t)(4 + b) * LSEQ + (j * 64 + i)) * DIMC;
    float va = b2f(outm[rA + c]);
    float vb = b2f(outm[rB + c]);
    float s1 = va, s2 = va * va, s3 = vb, s4 = vb * vb;
    for (int off = 32; off; off >>= 1) {
        s1 += __shfl_xor(s1, off, 64);
        s2 += __shfl_xor(s2, off, 64);
        s3 += __shfl_xor(s3, off, 64);
        s4 += __shfl_xor(s4, off, 64);
    }
    __shared__ float sm[4][4];
    int widx = c >> 6, lane = c & 63;
    if (lane == 0) { sm[widx][0] = s1; sm[widx][1] = s2; sm[widx][2] = s3; sm[widx][3] = s4; }
    __syncthreads();
    s1 = sm[0][0] + sm[1][0] + sm[2][0] + sm[3][0];
    s2 = sm[0][1] + sm[1][1] + sm[2][1] + sm[3][1];
    s3 = sm[0][2] + sm[1][2] + sm[2][2] + sm[3][2];
    s4 = sm[0][3] + sm[1][3] + sm[2][3] + sm[3][3];
    float muA = s1 * (1.0f / 256.0f), varA = s2 * (1.0f / 256.0f) - muA * muA;
    float muB = s3 * (1.0f / 256.0f), varB = s4 * (1.0f / 256.0f) - muB * muB;
    float lw = w[c], lb = bb[c];
    float ya = (va - muA) * rsqrtf(varA + 1e-6f) * lw + lb;
    float yb = (vb - muB) * rsqrtf(varB + 1e-6f) * lw + lb;
    float xo = x[(size_t)row * DIMC + c];
    out[(size_t)row * DIMC + c] = xo + ya + yb;
}

extern "C" void kernel_launch(void* const* d_in, const int* in_sizes, int n_in,
                              void* d_out, int out_size, void* d_ws, size_t ws_size,
                              hipStream_t stream) {
    const float* x      = (const float*)d_in[0];
    const float* ln1_w  = (const float*)d_in[1];
    const float* ln1_b  = (const float*)d_in[2];
    const float* ln2_w  = (const float*)d_in[3];
    const float* ln2_b  = (const float*)d_in[4];
    const float* W_in   = (const float*)d_in[5];
    const float* conv_w = (const float*)d_in[6];
    const float* conv_b = (const float*)d_in[7];
    const float* W_x    = (const float*)d_in[8];
    const float* W_dt   = (const float*)d_in[9];
    const float* b_dt   = (const float*)d_in[10];
    const float* A_log  = (const float*)d_in[11];
    const float* D_par  = (const float*)d_in[12];
    const float* W_out  = (const float*)d_in[13];
    float* out = (float*)d_out;

    // ---- workspace (~152 MB) ----
    char* ws = (char*)d_ws;
    size_t off = 0;
    ushort_t* wb_in  = (ushort_t*)(ws + off); off += (size_t)1024 * 256 * 2;
    ushort_t* wb_x   = (ushort_t*)(ws + off); off += (size_t)144 * 512 * 2;
    ushort_t* wb_out = (ushort_t*)(ws + off); off += (size_t)256 * 512 * 2;
    const size_t R0 = (size_t)MROWS * DIMC * 2;   // 16.78 MB
    const size_t R1 = (size_t)MROWS * 512 * 2;    // 33.55 MB
    ushort_t* r0 = (ushort_t*)(ws + off); off += R0;   // xm -> xdbl -> outm
    ushort_t* r1 = (ushort_t*)(ws + off); off += R1;   // xhalf -> dt_T
    ushort_t* r2 = (ushort_t*)(ws + off); off += R1;   // z
    ushort_t* r3 = (ushort_t*)(ws + off); off += R1;   // xc -> ys
    ushort_t* r4 = (ushort_t*)(ws + off); off += R1;   // u_T

    ushort_t* xm    = r0;
    ushort_t* xdbl  = r0;
    ushort_t* outm  = r0;
    ushort_t* xhalf = r1;
    ushort_t* dt_T  = r1;   // after xhalf dead (post-conv)
    ushort_t* zb    = r2;
    ushort_t* xc    = r3;   // ys after GEMM D
    ushort_t* u_T   = r4;

    // 0. convert MFMA weights fp32 -> bf16
    hipLaunchKernelGGL(cvtw, dim3((1024 * 256 + 255) / 256), dim3(256), 0, stream,
                       W_in, wb_in, 1024 * 256);
    hipLaunchKernelGGL(cvtw, dim3((144 * 512 + 255) / 256), dim3(256), 0, stream,
                       W_x, wb_x, 144 * 512);
    hipLaunchKernelGGL(cvtw, dim3((256 * 512 + 255) / 256), dim3(256), 0, stream,
                       W_out, wb_out, 256 * 512);

    // A. LayerNorm + dual-order xm
    hipLaunchKernelGGL(ln1_build_xm, dim3(4 * LSEQ), dim3(256), 0, stream,
                       x, ln1_w, ln1_b, xm);
    // B. xhalf = xm @ W_in[0:512]^T ; z = xm @ W_in[512:1024]^T
    hipLaunchKernelGGL(gemm_nt, dim3(MROWS / 64, 8), dim3(256), 0, stream,
                       xm, wb_in, xhalf, MROWS, 512, 256);
    hipLaunchKernelGGL(gemm_nt, dim3(MROWS / 64, 8), dim3(256), 0, stream,
                       xm, wb_in + (size_t)512 * 256, zb, MROWS, 512, 256);
    // C. conv + SiLU  (xhalf -> xc [bt,d] + u_T [b,d,t])
    hipLaunchKernelGGL(conv_silu, dim3((size_t)MROWS * 512 / 256), dim3(256), 0, stream,
                       xhalf, conv_w, conv_b, xc, u_T);
    // D. x_dbl = xc @ W_x^T   (N=144, K=512) -> region0
    hipLaunchKernelGGL(gemm_nt, dim3(MROWS / 64, 3), dim3(256), 0, stream,
                       xc, wb_x, xdbl, MROWS, 144, 512);
    // E. dt_T = softplus(dt_raw @ W_dt^T + b_dt)  [b,d,t] -> region1
    hipLaunchKernelGGL(dt_softplus, dim3((size_t)MROWS * 512 / 256), dim3(256), 0, stream,
                       xdbl, W_dt, b_dt, dt_T);
    // F. selective scan v2 (+ *silu(z) fused), ys written over xc
    hipLaunchKernelGGL(scan2, dim3(BS2 * 512 / 4), dim3(256), 0, stream,
                       dt_T, u_T, xdbl, zb, A_log, D_par, xc);
    // G. outm = ys @ W_out^T   (N=256, K=512) -> region0
    hipLaunchKernelGGL(gemm_nt, dim3(MROWS / 64, 4), dim3(256), 0, stream,
                       xc, wb_out, outm, MROWS, 256, 512);
    // H. final LN + transpose combine + residual (fp32 out)
    hipLaunchKernelGGL(final_ln_add, dim3(4 * LSEQ), dim3(256), 0, stream,
                       outm, x, ln2_w, ln2_b, out);
}

// Round 6
// 1986.299 us; speedup vs baseline: 1.9958x; 1.1681x over previous
//
#include <hip/hip_runtime.h>
#include <hip/hip_bf16.h>

typedef unsigned short ushort_t;
typedef unsigned int uint_t;
typedef __attribute__((ext_vector_type(8))) short short8;
typedef __attribute__((ext_vector_type(4))) float f32x4;

#define DIMC 256
#define D_INNER 512
#define D_STATE 64
#define DT_RANK 16
#define LSEQ 4096
#define BS2 8            // 2*BS batches through mamba
#define MROWS (BS2*LSEQ) // 32768

__device__ __forceinline__ float b2f(ushort_t u) {
    union { uint_t i; float f; } v; v.i = ((uint_t)u) << 16; return v.f;
}
__device__ __forceinline__ ushort_t f2b(float f) {
    union { float f; uint_t i; } v; v.f = f;
    uint_t r = v.i + 0x7FFFu + ((v.i >> 16) & 1u);   // RNE
    return (ushort_t)(r >> 16);
}
__device__ __forceinline__ float rdlane(float v, int l) {
    return __int_as_float(__builtin_amdgcn_readlane(__float_as_int(v), l));
}

// ---------------- fp32 -> bf16 weight conversion ----------------
__global__ void cvtw(const float* __restrict__ src, ushort_t* __restrict__ dst, int n) {
    int i = blockIdx.x * 256 + threadIdx.x;
    if (i < n) dst[i] = f2b(src[i]);
}

// ---------------- LN1 + build xm (both orders), fp32 in, bf16 out ----------------
__global__ void ln1_build_xm(const float* __restrict__ x,
                             const float* __restrict__ w,
                             const float* __restrict__ bb,
                             ushort_t* __restrict__ xm) {
    int row = blockIdx.x;            // b*4096 + l  (b in 0..3)
    int c = threadIdx.x;             // 0..255
    float v = x[(size_t)row * DIMC + c];
    float s1 = v, s2 = v * v;
    for (int off = 32; off; off >>= 1) {
        s1 += __shfl_xor(s1, off, 64);
        s2 += __shfl_xor(s2, off, 64);
    }
    __shared__ float sa[4], sb[4];
    int widx = c >> 6, lane = c & 63;
    if (lane == 0) { sa[widx] = s1; sb[widx] = s2; }
    __syncthreads();
    s1 = sa[0] + sa[1] + sa[2] + sa[3];
    s2 = sb[0] + sb[1] + sb[2] + sb[3];
    float mu = s1 * (1.0f / 256.0f);
    float var = s2 * (1.0f / 256.0f) - mu * mu;
    float xn = (v - mu) * rsqrtf(var + 1e-6f) * w[c] + bb[c];
    ushort_t o = f2b(xn);
    int b = row >> 12, l = row & 4095, i = l >> 6, j = l & 63;
    xm[((size_t)b * LSEQ + l) * DIMC + c] = o;
    xm[((size_t)(4 + b) * LSEQ + (j * 64 + i)) * DIMC + c] = o;
}

// ---------------- generic NT GEMM: C[M,N] = A[M,K] * W[N,K]^T (bf16 in/out) ----------------
__global__ void gemm_nt(const ushort_t* __restrict__ A,
                        const ushort_t* __restrict__ W,
                        ushort_t* __restrict__ C, int M, int N, int K) {
    int tid = threadIdx.x;
    int lane = tid & 63, widx = tid >> 6;
    int m0 = blockIdx.x * 64 + widx * 16;
    int n0 = blockIdx.y * 64;
    int l16 = lane & 15, quad = lane >> 4;
    f32x4 acc[4] = {f32x4{0,0,0,0}, f32x4{0,0,0,0}, f32x4{0,0,0,0}, f32x4{0,0,0,0}};
    const ushort_t* arow = A + (size_t)(m0 + l16) * K + quad * 8;
    bool nv[4];
    for (int j = 0; j < 4; ++j) nv[j] = (n0 + j * 16) < N;
    for (int k0 = 0; k0 < K; k0 += 32) {
        short8 af = *(const short8*)(arow + k0);
        #pragma unroll
        for (int j = 0; j < 4; ++j) {
            if (nv[j]) {
                const ushort_t* wrow = W + (size_t)(n0 + j * 16 + l16) * K + quad * 8 + k0;
                short8 bf = *(const short8*)wrow;
                acc[j] = __builtin_amdgcn_mfma_f32_16x16x32_bf16(af, bf, acc[j], 0, 0, 0);
            }
        }
    }
    #pragma unroll
    for (int j = 0; j < 4; ++j) {
        if (!nv[j]) continue;
        int col = n0 + j * 16 + l16;
        #pragma unroll
        for (int r = 0; r < 4; ++r) {
            int row = m0 + quad * 4 + r;
            C[(size_t)row * N + col] = f2b(acc[j][r]);
        }
    }
}

// ---------------- tiled conv(4)+SiLU: all-coalesced, dual output ----------------
// grid (MROWS/64, 512/64); writes xc[bt,d] AND u_T[b,d,t], both coalesced
__global__ void conv_silu_t(const ushort_t* __restrict__ xh,
                            const float* __restrict__ cw,
                            const float* __restrict__ cb,
                            ushort_t* __restrict__ xc,
                            ushort_t* __restrict__ u_T) {
    int bt0 = blockIdx.x * 64;       // 64-row t-tile, never crosses batch
    int d0  = blockIdx.y * 64;
    int b   = bt0 >> 12;
    int t0  = bt0 & 4095;
    __shared__ ushort_t tin[67][66];   // rows t0-3..t0+63; stride 33 dwords (conflict-free)
    __shared__ ushort_t tout[64][66];
    int tid = threadIdx.x, lane = tid & 63, widx = tid >> 6;
    for (int r = widx; r < 67; r += 4) {
        int tt = t0 - 3 + r;
        tin[r][lane] = (tt >= 0) ? xh[((size_t)bt0 - 3 + r) * 512 + d0 + lane] : (ushort_t)0;
    }
    __syncthreads();
    // compute: lane = t_local, loop over d
    for (int dd = widx; dd < 64; dd += 4) {
        int d = d0 + dd;
        float acc = cb[d];
        #pragma unroll
        for (int k = 0; k < 4; ++k)
            acc += cw[d * 4 + k] * b2f(tin[lane + k][dd]);
        float s = acc / (1.0f + __expf(-acc));
        ushort_t o = f2b(s);
        u_T[((size_t)b * 512 + d) * 4096 + t0 + lane] = o;   // coalesced (lane=t)
        tout[lane][dd] = o;
    }
    __syncthreads();
    // write xc[bt,d]: lane = d
    for (int r = widx; r < 64; r += 4)
        xc[((size_t)bt0 + r) * 512 + d0 + lane] = tout[r][lane];
}

// ---------------- tiled dt = softplus(xdbl[:, :16] @ W_dt^T + b_dt) -> dt_T ----------------
// grid (MROWS/64, 512/64)
__global__ void dt_sp_t(const ushort_t* __restrict__ xdbl,
                        const float* __restrict__ wdt,
                        const float* __restrict__ bdt,
                        ushort_t* __restrict__ dt_T) {
    int bt0 = blockIdx.x * 64;
    int d0  = blockIdx.y * 64;
    int b   = bt0 >> 12;
    int t0  = bt0 & 4095;
    __shared__ float din[64][17];    // stride 17 dwords (conflict-free)
    int tid = threadIdx.x;
    for (int i = tid; i < 64 * 16; i += 256) {
        int r = i >> 4, k = i & 15;
        din[r][k] = b2f(xdbl[((size_t)bt0 + r) * 144 + k]);
    }
    __syncthreads();
    int lane = tid & 63, widx = tid >> 6;
    for (int dd = widx; dd < 64; dd += 4) {
        int d = d0 + dd;                     // wave-uniform -> s_loads for wdt/bdt
        float acc = bdt[d];
        #pragma unroll
        for (int k = 0; k < 16; ++k)
            acc += din[lane][k] * wdt[d * 16 + k];
        float sp = (acc > 20.0f) ? acc : log1pf(__expf(acc));
        dt_T[((size_t)b * 512 + d) * 4096 + t0 + lane] = f2b(sp);   // coalesced
    }
}

// ---------------- selective scan v3: wave per (b,d), 64-t chunks, coalesced I/O ----------------
// uT_ysT: reads u chunk, then overwrites same addresses with ungated y (in place)
__global__ void scan3(const ushort_t* __restrict__ dt_T,
                      ushort_t* uT_ysT,
                      const ushort_t* __restrict__ xdbl,
                      const float* __restrict__ Alog,
                      const float* __restrict__ Dp) {
    int wid = blockIdx.x * 4 + (threadIdx.x >> 6);  // 0..4095
    int lane = threadIdx.x & 63;
    int b = wid >> 9, d = wid & 511;
    float a = -__expf(Alog[d * 64 + lane]);
    float Dd = Dp[d];
    float h = 0.0f;
    size_t rowT = ((size_t)b * 512 + d) * 4096;
    size_t base = (size_t)b * LSEQ;
    for (int t0 = 0; t0 < LSEQ; t0 += 64) {
        float dtv = b2f(dt_T[rowT + t0 + lane]);    // coalesced, lane=t
        float uv  = b2f(uT_ysT[rowT + t0 + lane]);  // coalesced, lane=t
        float wv  = dtv * uv;
        float p[64];
        #pragma unroll
        for (int j = 0; j < 64; ++j) {
            size_t r = (base + t0 + j) * 144;
            float Bv = b2f(xdbl[r + 16 + lane]);
            float Cv = b2f(xdbl[r + 80 + lane]);
            float dtb = rdlane(dtv, j);
            float wtb = rdlane(wv, j);
            float dA = __expf(dtb * a);
            h = dA * h + wtb * Bv;
            p[j] = h * Cv;
        }
        // butterfly transpose-reduce over s; result for t = t0+lane lands on lane
        #pragma unroll
        for (int mask = 32; mask >= 1; mask >>= 1) {
            bool up = (lane & mask) != 0;
            #pragma unroll
            for (int j2 = 0; j2 < mask; ++j2) {
                float send = up ? p[j2] : p[j2 + mask];
                float recv = __shfl_xor(send, mask, 64);
                float keep = up ? p[j2 + mask] : p[j2];
                p[j2] = keep + recv;
            }
        }
        float y = p[0] + uv * Dd;                   // ungated
        uT_ysT[rowT + t0 + lane] = f2b(y);          // coalesced in-place store
    }
}

// ---------------- gate + transpose: ys[bt,d] = ysT[b,d,t] * silu(z[bt,d]) ----------------
// grid (MROWS/64, 512/64)
__global__ void gate_t(const ushort_t* __restrict__ ysT,
                       const ushort_t* __restrict__ zb,
                       ushort_t* __restrict__ ys) {
    int bt0 = blockIdx.x * 64;
    int d0  = blockIdx.y * 64;
    int b   = bt0 >> 12;
    int t0  = bt0 & 4095;
    __shared__ ushort_t tile[64][66];
    int tid = threadIdx.x, lane = tid & 63, widx = tid >> 6;
    for (int dd = widx; dd < 64; dd += 4)
        tile[dd][lane] = ysT[((size_t)b * 512 + d0 + dd) * 4096 + t0 + lane];  // coalesced
    __syncthreads();
    for (int r = widx; r < 64; r += 4) {
        float zv = b2f(zb[((size_t)bt0 + r) * 512 + d0 + lane]);               // coalesced
        float yv = b2f(tile[lane][r]);                                          // conflict-free
        float g = zv / (1.0f + __expf(-zv));
        ys[((size_t)bt0 + r) * 512 + d0 + lane] = f2b(yv * g);                 // coalesced
    }
}

// ---------------- final LN + transpose-combine + residual (fp32 out) ----------------
__global__ void final_ln_add(const ushort_t* __restrict__ outm,
                             const float* __restrict__ x,
                             const float* __restrict__ w,
                             const float* __restrict__ bb,
                             float* __restrict__ out) {
    int row = blockIdx.x;   // b*4096 + l, b in 0..3
    int c = threadIdx.x;
    int b = row >> 12, l = row & 4095, i = l >> 6, j = l & 63;
    size_t rA = ((size_t)b * LSEQ + l) * DIMC;
    size_t rB = ((size_t)(4 + b) * LSEQ + (j * 64 + i)) * DIMC;
    float va = b2f(outm[rA + c]);
    float vb = b2f(outm[rB + c]);
    float s1 = va, s2 = va * va, s3 = vb, s4 = vb * vb;
    for (int off = 32; off; off >>= 1) {
        s1 += __shfl_xor(s1, off, 64);
        s2 += __shfl_xor(s2, off, 64);
        s3 += __shfl_xor(s3, off, 64);
        s4 += __shfl_xor(s4, off, 64);
    }
    __shared__ float sm[4][4];
    int widx = c >> 6, lane = c & 63;
    if (lane == 0) { sm[widx][0] = s1; sm[widx][1] = s2; sm[widx][2] = s3; sm[widx][3] = s4; }
    __syncthreads();
    s1 = sm[0][0] + sm[1][0] + sm[2][0] + sm[3][0];
    s2 = sm[0][1] + sm[1][1] + sm[2][1] + sm[3][1];
    s3 = sm[0][2] + sm[1][2] + sm[2][2] + sm[3][2];
    s4 = sm[0][3] + sm[1][3] + sm[2][3] + sm[3][3];
    float muA = s1 * (1.0f / 256.0f), varA = s2 * (1.0f / 256.0f) - muA * muA;
    float muB = s3 * (1.0f / 256.0f), varB = s4 * (1.0f / 256.0f) - muB * muB;
    float lw = w[c], lb = bb[c];
    float ya = (va - muA) * rsqrtf(varA + 1e-6f) * lw + lb;
    float yb = (vb - muB) * rsqrtf(varB + 1e-6f) * lw + lb;
    float xo = x[(size_t)row * DIMC + c];
    out[(size_t)row * DIMC + c] = xo + ya + yb;
}

extern "C" void kernel_launch(void* const* d_in, const int* in_sizes, int n_in,
                              void* d_out, int out_size, void* d_ws, size_t ws_size,
                              hipStream_t stream) {
    const float* x      = (const float*)d_in[0];
    const float* ln1_w  = (const float*)d_in[1];
    const float* ln1_b  = (const float*)d_in[2];
    const float* ln2_w  = (const float*)d_in[3];
    const float* ln2_b  = (const float*)d_in[4];
    const float* W_in   = (const float*)d_in[5];
    const float* conv_w = (const float*)d_in[6];
    const float* conv_b = (const float*)d_in[7];
    const float* W_x    = (const float*)d_in[8];
    const float* W_dt   = (const float*)d_in[9];
    const float* b_dt   = (const float*)d_in[10];
    const float* A_log  = (const float*)d_in[11];
    const float* D_par  = (const float*)d_in[12];
    const float* W_out  = (const float*)d_in[13];
    float* out = (float*)d_out;

    // ---- workspace (~152 MB) ----
    char* ws = (char*)d_ws;
    size_t off = 0;
    ushort_t* wb_in  = (ushort_t*)(ws + off); off += (size_t)1024 * 256 * 2;
    ushort_t* wb_x   = (ushort_t*)(ws + off); off += (size_t)144 * 512 * 2;
    ushort_t* wb_out = (ushort_t*)(ws + off); off += (size_t)256 * 512 * 2;
    const size_t R0 = (size_t)MROWS * DIMC * 2;   // 16.78 MB
    const size_t R1 = (size_t)MROWS * 512 * 2;    // 33.55 MB
    ushort_t* r0 = (ushort_t*)(ws + off); off += R0;   // xm -> xdbl -> outm
    ushort_t* r1 = (ushort_t*)(ws + off); off += R1;   // xhalf -> dt_T
    ushort_t* r2 = (ushort_t*)(ws + off); off += R1;   // z
    ushort_t* r3 = (ushort_t*)(ws + off); off += R1;   // xc -> ys (gated)
    ushort_t* r4 = (ushort_t*)(ws + off); off += R1;   // u_T -> ysT (in place)

    ushort_t* xm    = r0;
    ushort_t* xdbl  = r0;
    ushort_t* outm  = r0;
    ushort_t* xhalf = r1;
    ushort_t* dt_T  = r1;
    ushort_t* zb    = r2;
    ushort_t* xc    = r3;
    ushort_t* ys    = r3;
    ushort_t* u_T   = r4;   // becomes ysT in place

    // 0. convert MFMA weights fp32 -> bf16
    hipLaunchKernelGGL(cvtw, dim3((1024 * 256 + 255) / 256), dim3(256), 0, stream,
                       W_in, wb_in, 1024 * 256);
    hipLaunchKernelGGL(cvtw, dim3((144 * 512 + 255) / 256), dim3(256), 0, stream,
                       W_x, wb_x, 144 * 512);
    hipLaunchKernelGGL(cvtw, dim3((256 * 512 + 255) / 256), dim3(256), 0, stream,
                       W_out, wb_out, 256 * 512);

    // A. LayerNorm + dual-order xm
    hipLaunchKernelGGL(ln1_build_xm, dim3(4 * LSEQ), dim3(256), 0, stream,
                       x, ln1_w, ln1_b, xm);
    // B. xhalf = xm @ W_in[0:512]^T ; z = xm @ W_in[512:1024]^T
    hipLaunchKernelGGL(gemm_nt, dim3(MROWS / 64, 8), dim3(256), 0, stream,
                       xm, wb_in, xhalf, MROWS, 512, 256);
    hipLaunchKernelGGL(gemm_nt, dim3(MROWS / 64, 8), dim3(256), 0, stream,
                       xm, wb_in + (size_t)512 * 256, zb, MROWS, 512, 256);
    // C. tiled conv + SiLU: xhalf -> xc[bt,d] + u_T[b,d,t]
    hipLaunchKernelGGL(conv_silu_t, dim3(MROWS / 64, 8), dim3(256), 0, stream,
                       xhalf, conv_w, conv_b, xc, u_T);
    // D. x_dbl = xc @ W_x^T   (N=144, K=512) -> region0
    hipLaunchKernelGGL(gemm_nt, dim3(MROWS / 64, 3), dim3(256), 0, stream,
                       xc, wb_x, xdbl, MROWS, 144, 512);
    // E. tiled dt_T = softplus(...)  [b,d,t] -> region1
    hipLaunchKernelGGL(dt_sp_t, dim3(MROWS / 64, 8), dim3(256), 0, stream,
                       xdbl, W_dt, b_dt, dt_T);
    // F. selective scan v3: u_T -> ysT in place
    hipLaunchKernelGGL(scan3, dim3(BS2 * 512 / 4), dim3(256), 0, stream,
                       dt_T, u_T, xdbl, A_log, D_par);
    // G. gate + transpose: ys[bt,d] = ysT * silu(z)
    hipLaunchKernelGGL(gate_t, dim3(MROWS / 64, 8), dim3(256), 0, stream,
                       u_T, zb, ys);
    // H. outm = ys @ W_out^T   (N=256, K=512) -> region0
    hipLaunchKernelGGL(gemm_nt, dim3(MROWS / 64, 4), dim3(256), 0, stream,
                       ys, wb_out, outm, MROWS, 256, 512);
    // I. final LN + transpose combine + residual (fp32 out)
    hipLaunchKernelGGL(final_ln_add, dim3(4 * LSEQ), dim3(256), 0, stream,
                       outm, x, ln2_w, ln2_b, out);
}